// Round 10
// baseline (33888.828 us; speedup 1.0000x reference)
//
#include <hip/hip_runtime.h>

// Persistent-LSTM MI355X — Round 16: R14 + 8x tag replication (poller fan-out).
// R15's data-first fast path REGRESSED (33.7ms): the period-setting producer
// is the globally-LAST one, whose words are never valid at spec-read time —
// fast path can't fire on the critical chain, and its spec-tag check
// serialized spec-read-L ahead of the gate. R14 (30.0ms) restored verbatim.
// R16's single variable: all 256 consumer blocks' wave-wv polled the SAME
// 2 tag lines (256 pollers/line-pair) — the producer's tag store lands on a
// line with a deep read queue, inflating visibility + detect jitter, which
// the max-of-256 straggler statistic amplifies 2-3x (session law 5).
// Now: slots[8][256] replicas; producer stores its tag to all 8 (lanes 0-7
// of wave 0, AFTER barrier #2 — publish ordering unchanged); consumer block
// B polls replica B>>5 only. Pollers/line: 256 -> 32. Data single-copy
// (law 1: replication of DATA was R13's 134GB death; tags are 4B/block).
// Session laws (all respected):
//   (1) h written ONCE, pulled via LLC (R13)
//   (2) publish: word stores -> __syncthreads drain -> tag stores (R7/8/10/12)
//   (3) sleep-paced compact-tag gate; spec data read overlaps gate (R14)
//   (4) geometry 256x512, weights VGPR-resident (R9)
//   (5) straggler-max amplifies per-wave latency savings 2-3x (R11/R14)
// 0xAA ws poison: negative signed tag -> stale/inert (R3-R15 validated).
// ws: hq u64[2][2048] (32KB) + slots u32[8][256] (8KB).

#define H      2048
#define TSTEPS 8192
#define FEAT   128
#define NBLK   256
#define NTHR   512

typedef float vf4 __attribute__((ext_vector_type(4)));
typedef float vf2 __attribute__((ext_vector_type(2)));
typedef unsigned long long u64;
typedef unsigned int u32;

__device__ __forceinline__ float sigm(float xv) {
  return __builtin_amdgcn_rcpf(1.0f + __expf(-xv));
}
__device__ __forceinline__ float tanh_(float xv) {
  return 1.0f - 2.0f * __builtin_amdgcn_rcpf(__expf(2.0f * xv) + 1.0f);
}

__device__ __forceinline__ u64 aload64(const u64* p) {
  return __hip_atomic_load(p, __ATOMIC_RELAXED, __HIP_MEMORY_SCOPE_AGENT);
}
__device__ __forceinline__ u32 aload32(const u32* p) {
  return __hip_atomic_load(p, __ATOMIC_RELAXED, __HIP_MEMORY_SCOPE_AGENT);
}
__device__ __forceinline__ void astoreu(u32* p, u32 v) {
  __hip_atomic_store(p, v, __ATOMIC_RELAXED, __HIP_MEMORY_SCOPE_AGENT);
}
__device__ __forceinline__ void astore64(u64* p, u64 v) {
  __hip_atomic_store(p, v, __ATOMIC_RELAXED, __HIP_MEMORY_SCOPE_AGENT);
}
__device__ __forceinline__ int  tag_of(u64 d) { return (int)(u32)(d >> 32); }
__device__ __forceinline__ float val_of(u64 d) { return __uint_as_float((u32)d); }
__device__ __forceinline__ u64  pack(int tag, float v) {
  return ((u64)(u32)tag << 32) | (u64)__float_as_uint(v);
}

#define DECLG(g) vf4 w##g##_0, w##g##_1, w##g##_2, w##g##_3, \
                     w##g##_4, w##g##_5, w##g##_6, w##g##_7; \
                 vf2 wih##g; float bias##g; float acc##g;

#define LOADG(g) { \
  const int row_ = (g) * H + j; \
  const float* wr_ = W_hh + (long)row_ * H; \
  w##g##_0 = *(const vf4*)(wr_ + 4*(ln      )); \
  w##g##_1 = *(const vf4*)(wr_ + 4*(ln +  64)); \
  w##g##_2 = *(const vf4*)(wr_ + 4*(ln + 128)); \
  w##g##_3 = *(const vf4*)(wr_ + 4*(ln + 192)); \
  w##g##_4 = *(const vf4*)(wr_ + 4*(ln + 256)); \
  w##g##_5 = *(const vf4*)(wr_ + 4*(ln + 320)); \
  w##g##_6 = *(const vf4*)(wr_ + 4*(ln + 384)); \
  w##g##_7 = *(const vf4*)(wr_ + 4*(ln + 448)); \
  wih##g  = *(const vf2*)(W_ih + (long)row_ * FEAT + 2*ln); \
  bias##g = b_ih[row_] + b_hh[row_]; }

// Opaque pin: weights become non-rematerializable (cannot re-sink into loop).
#define PIN(g) asm volatile("" : \
  "+v"(w##g##_0), "+v"(w##g##_1), "+v"(w##g##_2), "+v"(w##g##_3), \
  "+v"(w##g##_4), "+v"(w##g##_5), "+v"(w##g##_6), "+v"(w##g##_7), \
  "+v"(wih##g), "+v"(bias##g));

#define LDSREAD(k, ldsrow) \
  const vf4 hv##k = *(const vf4*)&(ldsrow)[4*(ln + 64*(k))];

#define FMA_G(g, c) \
  acc##g = __builtin_fmaf(w##g##_##c.x, h4_.x, acc##g); \
  acc##g = __builtin_fmaf(w##g##_##c.y, h4_.y, acc##g); \
  acc##g = __builtin_fmaf(w##g##_##c.z, h4_.z, acc##g); \
  acc##g = __builtin_fmaf(w##g##_##c.w, h4_.w, acc##g);

#define FMA_C(c) { const vf4 h4_ = hv##c; \
  FMA_G(0, c) FMA_G(1, c) FMA_G(2, c) FMA_G(3, c) }

#define REDUCE(g) { float a_ = acc##g; \
  a_ += __shfl_xor(a_, 1);  a_ += __shfl_xor(a_, 2);  a_ += __shfl_xor(a_, 4); \
  a_ += __shfl_xor(a_, 8);  a_ += __shfl_xor(a_, 16); a_ += __shfl_xor(a_, 32); \
  acc##g = a_ + bias##g; }

// Wave wv (R14 verbatim, gate reads from this block's tag REPLICA):
// (1) issue 4 speculative slice-word loads (in flight during the gate);
// (2) 3-deep pipelined compact-tag gate over its 32 producers (2 lines of
//     the replica polled by only 32 waves device-wide);
// (3) validate in-flight words; re-read stale ones (bounded: gate-pass =>
//     all words visible => first re-read fresh); (4) stage to LDS.
__device__ __forceinline__ void poll_and_stage(const u32* __restrict__ sg,
                                               const u64* __restrict__ hq_par,
                                               int tgt,
                                               float* __restrict__ ldsrow,
                                               int wv, int ln) {
  const int base = wv * 256 + 4 * ln;
  const u64* hp = hq_par + base;
  u64 d0 = aload64(hp + 0);          // speculative: in flight during poll
  u64 d1 = aload64(hp + 1);
  u64 d2 = aload64(hp + 2);
  u64 d3 = aload64(hp + 3);

  const u32* sp = sg + wv * 32 + (ln & 31);
  const bool act = (ln < 32);
  int v0 = act ? (int)aload32(sp) : 0x7fffffff;
  int v1 = act ? (int)aload32(sp) : 0x7fffffff;
  int v2 = act ? (int)aload32(sp) : 0x7fffffff;
  while (!__all(v0 >= tgt)) {
    __builtin_amdgcn_s_sleep(1);
    v0 = v1;
    v1 = v2;
    v2 = (act && v1 < tgt) ? (int)aload32(sp) : v1;
  }
  // gate passed: all words visible; validate the speculative data.
  while (!__all((tag_of(d0) >= tgt) & (tag_of(d1) >= tgt) &
                (tag_of(d2) >= tgt) & (tag_of(d3) >= tgt))) {
    if (tag_of(d0) < tgt) d0 = aload64(hp + 0);
    if (tag_of(d1) < tgt) d1 = aload64(hp + 1);
    if (tag_of(d2) < tgt) d2 = aload64(hp + 2);
    if (tag_of(d3) < tgt) d3 = aload64(hp + 3);
  }
  vf4 hv;
  hv.x = val_of(d0);
  hv.y = val_of(d1);
  hv.z = val_of(d2);
  hv.w = val_of(d3);
  *(vf4*)&ldsrow[base] = hv;
}

__global__ __launch_bounds__(NTHR, 2)
void lstm_persist(const float* __restrict__ x,
                  const float* __restrict__ W_ih,
                  const float* __restrict__ W_hh,
                  const float* __restrict__ b_ih,
                  const float* __restrict__ b_hh,
                  const float* __restrict__ W_lin,
                  const float* __restrict__ b_lin,
                  const float* __restrict__ W_out,
                  const float* __restrict__ b_out,
                  float* __restrict__ out,
                  float* __restrict__ ws)
{
  const int tid = threadIdx.x;
  const int b   = blockIdx.x;
  const int wv  = tid >> 6;
  const int ln  = tid & 63;

  // ws: u64 hq[2][H] tagged h words (32KB); parity p serves steps t&1==p;
  // hq[1] reused for ylin (tag TSTEPS+1). slots: u32[8][256] tag replicas;
  // consumer block B polls replica B>>5; head phases use replica 0.
  u64* hq    = (u64*)ws;
  u32* slots = (u32*)(ws + 4 * H);
  const u32* sg = slots + ((b >> 5) << 8);   // this block's replica

  __shared__ __align__(16) float h_lds[2][H];

  // h_0 = 0: zero parity-0 LDS row (512 threads x 16B)
  *(vf4*)&h_lds[0][4 * tid] = (vf4)(0.0f);

  // ---- persistent weights: load then pin ----
  const int j = b * 8 + wv;
  DECLG(0) DECLG(1) DECLG(2) DECLG(3)
  LOADG(0) LOADG(1) LOADG(2) LOADG(3)
  PIN(0) PIN(1) PIN(2) PIN(3)

  __syncthreads();

  float cst = 0.0f;

  #pragma unroll 1
  for (int t = 0; t < TSTEPS; ++t) {
    const vf2 xr = *(const vf2*)(x + (long)t * FEAT + 2 * ln);
    float* ldsrow = h_lds[t & 1];

    if (t > 0)
      poll_and_stage(sg, hq + (t & 1) * H, t, ldsrow, wv, ln);
    __syncthreads();   // barrier #1: all slices staged before any LDS read

    LDSREAD(0, ldsrow) LDSREAD(1, ldsrow) LDSREAD(2, ldsrow) LDSREAD(3, ldsrow)
    LDSREAD(4, ldsrow) LDSREAD(5, ldsrow) LDSREAD(6, ldsrow) LDSREAD(7, ldsrow)

    acc0 = wih0.x * xr.x + wih0.y * xr.y;
    acc1 = wih1.x * xr.x + wih1.y * xr.y;
    acc2 = wih2.x * xr.x + wih2.y * xr.y;
    acc3 = wih3.x * xr.x + wih3.y * xr.y;

    FMA_C(0) FMA_C(1) FMA_C(2) FMA_C(3)
    FMA_C(4) FMA_C(5) FMA_C(6) FMA_C(7)

    REDUCE(0) REDUCE(1) REDUCE(2) REDUCE(3)

    // gate order [i, f, g, o]
    const float iv = sigm(acc0);
    const float fv = sigm(acc1);
    const float gv = tanh_(acc2);
    const float ov = sigm(acc3);
    cst = fv * cst + iv * gv;
    const float hval = ov * tanh_(cst);

    // publish h_{t+1} (R6-validated ordering, u64 self-validating word):
    // word store -> __syncthreads (drains vmcnt per wave) -> tag stores.
    // Lanes 0-7 of wave 0 fan the tag out to all 8 replicas (one line each;
    // monotonic >= semantics make any store reordering harmless).
    if (ln == 0)
      astore64(hq + ((t + 1) & 1) * H + j, pack(t + 1, hval));
    __syncthreads();   // barrier #2: all 8 words visible before tags below
    if (wv == 0 && ln < 8)
      astoreu(slots + (ln << 8) + b, (u32)(t + 1));
  }

  // ---- head phase 1: ylin[j] = b_lin[j] + dot(W_lin[j,:], h_final) ----
  // h_final words: parity 0, tag TSTEPS. Passing the gate/validation for
  // tag TSTEPS implies every block finished its step-8191 parity-1 reads ->
  // ylin store into hq[1] is WAR-safe.
  {
    float* ldsrow = h_lds[0];
    poll_and_stage(sg, hq, TSTEPS, ldsrow, wv, ln);
    __syncthreads();

    float a0 = 0.0f;
    const float* wl = W_lin + (long)j * H;
    #pragma unroll
    for (int k = 0; k < 8; ++k) {
      const vf4 h4 = *(const vf4*)&ldsrow[4 * (ln + 64 * k)];
      const vf4 u  = *(const vf4*)(wl + 4 * (ln + 64 * k));
      a0 += u.x * h4.x + u.y * h4.y + u.z * h4.z + u.w * h4.w;
    }
    a0 += __shfl_xor(a0, 1);  a0 += __shfl_xor(a0, 2);  a0 += __shfl_xor(a0, 4);
    a0 += __shfl_xor(a0, 8);  a0 += __shfl_xor(a0, 16); a0 += __shfl_xor(a0, 32);

    if (ln == 0)
      astore64(hq + H + j, pack(TSTEPS + 1, a0 + b_lin[j]));  // ylin word
    __syncthreads();   // drains vmcnt -> ylin visible before tag below
    if (tid == 0)
      astoreu(slots + b, (u32)(TSTEPS + 1));   // replica 0 (head-2 is b==0)
  }

  // ---- head phase 2: y = ylin @ W_out.T + b_out (block 0, wave 0) ----
  // Barrier-ordered slot protocol on replica 0; reads after gate (fresh).
  if (b == 0 && wv == 0) {
    const u32* sp = slots + 4 * ln;
    int v0 = (int)aload32(sp + 0), v1 = (int)aload32(sp + 1);
    int v2 = (int)aload32(sp + 2), v3 = (int)aload32(sp + 3);
    const int tgt = TSTEPS + 1;
    while (!__all((v0 >= tgt) & (v1 >= tgt) & (v2 >= tgt) & (v3 >= tgt))) {
      __builtin_amdgcn_s_sleep(1);
      if (v0 < tgt) v0 = (int)aload32(sp + 0);
      if (v1 < tgt) v1 = (int)aload32(sp + 1);
      if (v2 < tgt) v2 = (int)aload32(sp + 2);
      if (v3 < tgt) v3 = (int)aload32(sp + 3);
    }
    float p0 = 0.0f, p1 = 0.0f;
    #pragma unroll
    for (int k = 0; k < 32; ++k) {
      const u64 d  = aload64(hq + H + ln + 64 * k);
      const float y = val_of(d);
      const int c  = ln + 64 * k;
      p0 = __builtin_fmaf(W_out[c],     y, p0);
      p1 = __builtin_fmaf(W_out[H + c], y, p1);
    }
    p0 += __shfl_xor(p0, 1);  p0 += __shfl_xor(p0, 2);  p0 += __shfl_xor(p0, 4);
    p0 += __shfl_xor(p0, 8);  p0 += __shfl_xor(p0, 16); p0 += __shfl_xor(p0, 32);
    p1 += __shfl_xor(p1, 1);  p1 += __shfl_xor(p1, 2);  p1 += __shfl_xor(p1, 4);
    p1 += __shfl_xor(p1, 8);  p1 += __shfl_xor(p1, 16); p1 += __shfl_xor(p1, 32);
    if (ln == 0) {
      out[0] = p0 + b_out[0];
      out[1] = p1 + b_out[1];
    }
  }
}

extern "C" void kernel_launch(void* const* d_in, const int* in_sizes, int n_in,
                              void* d_out, int out_size, void* d_ws, size_t ws_size,
                              hipStream_t stream) {
  const float* x     = (const float*)d_in[0];
  const float* W_ih  = (const float*)d_in[1];
  const float* W_hh  = (const float*)d_in[2];
  const float* b_ih  = (const float*)d_in[3];
  const float* b_hh  = (const float*)d_in[4];
  const float* W_lin = (const float*)d_in[5];
  const float* b_lin = (const float*)d_in[6];
  const float* W_out = (const float*)d_in[7];
  const float* b_out = (const float*)d_in[8];

  lstm_persist<<<dim3(NBLK), dim3(NTHR), 0, stream>>>(
      x, W_ih, W_hh, b_ih, b_hh, W_lin, b_lin, W_out, b_out,
      (float*)d_out, (float*)d_ws);
}